// Round 1
// baseline (1998.414 us; speedup 1.0000x reference)
//
#include <hip/hip_runtime.h>
#include <math.h>

#define NN 50000
#define NE 800000
#define EPSV 1e-5f

// ---------------- degree count ----------------
__global__ void deg_kernel(const int* __restrict__ dst, int* __restrict__ deg, int E) {
    int e = blockIdx.x * blockDim.x + threadIdx.x;
    if (e < E) atomicAdd(&deg[dst[e]], 1);
}

// ---------------- dense per-node matmuls: Ya = x@W[0], Yb = x@W[1], Z = x@R + B ----------------
template<int CIN, int COUT>
__global__ void matmul3_kernel(const float* __restrict__ x,
                               const float* __restrict__ W,   // (2, CIN, COUT)
                               const float* __restrict__ R,   // (CIN, COUT)
                               const float* __restrict__ Bb,  // (COUT)
                               float* __restrict__ Ya,
                               float* __restrict__ Yb,
                               float* __restrict__ Z,
                               int n_nodes) {
    int tid = blockIdx.x * blockDim.x + threadIdx.x;
    if (tid >= n_nodes * COUT) return;
    int n = tid / COUT;
    int o = tid - n * COUT;
    const float* xr = x + n * CIN;
    float a = 0.f, b = 0.f, z = 0.f;
#pragma unroll
    for (int c = 0; c < CIN; ++c) {
        float xv = xr[c];
        a = fmaf(xv, W[c * COUT + o], a);
        b = fmaf(xv, W[CIN * COUT + c * COUT + o], b);
        z = fmaf(xv, R[c * COUT + o], z);
    }
    Ya[tid] = a;
    Yb[tid] = b;
    Z[tid]  = z + Bb[o];
}

// ---------------- edge scatter, COUT=64: 16 threads per edge, float4 each ----------------
__global__ void scatter64_kernel(const int* __restrict__ src, const int* __restrict__ dst,
                                 const float* __restrict__ attr,
                                 const float* __restrict__ Ya, const float* __restrict__ Yb,
                                 float* __restrict__ agg, int E) {
    int tid = blockIdx.x * blockDim.x + threadIdx.x;
    int e = tid >> 4;
    if (e >= E) return;
    int q = (tid & 15) << 2;
    int s = src[e], d = dst[e];
    float u = attr[e];
    float w0 = 1.f - u;
    const float4 ya = *reinterpret_cast<const float4*>(Ya + s * 64 + q);
    const float4 yb = *reinterpret_cast<const float4*>(Yb + s * 64 + q);
    float* ap = agg + d * 64 + q;
    atomicAdd(ap + 0, fmaf(w0, ya.x, u * yb.x));
    atomicAdd(ap + 1, fmaf(w0, ya.y, u * yb.y));
    atomicAdd(ap + 2, fmaf(w0, ya.z, u * yb.z));
    atomicAdd(ap + 3, fmaf(w0, ya.w, u * yb.w));
}

// ---------------- edge scatter, COUT=7: 1 thread per edge ----------------
__global__ void scatter7_kernel(const int* __restrict__ src, const int* __restrict__ dst,
                                const float* __restrict__ attr,
                                const float* __restrict__ Ya, const float* __restrict__ Yb,
                                float* __restrict__ agg, int E) {
    int e = blockIdx.x * blockDim.x + threadIdx.x;
    if (e >= E) return;
    int s = src[e], d = dst[e];
    float u = attr[e];
    float w0 = 1.f - u;
#pragma unroll
    for (int c = 0; c < 7; ++c) {
        atomicAdd(&agg[d * 7 + c], fmaf(w0, Ya[s * 7 + c], u * Yb[s * 7 + c]));
    }
}

// ---------------- combine + BN + ELU (H=64 layers) ----------------
__global__ void bn_elu_kernel(const float* __restrict__ agg, const float* __restrict__ Z,
                              const int* __restrict__ deg,
                              const float* __restrict__ G, const float* __restrict__ BE,
                              const float* __restrict__ RM, const float* __restrict__ RV,
                              float* __restrict__ h, int n_nodes) {
    int tid = blockIdx.x * blockDim.x + threadIdx.x;
    if (tid >= n_nodes * 64) return;
    int n = tid >> 6;
    int f = tid & 63;
    float degv = (float)deg[n];
    if (degv < 1.f) degv = 1.f;
    float v = agg[tid] / degv + Z[tid];
    v = (v - RM[f]) * rsqrtf(RV[f] + EPSV) * G[f] + BE[f];
    h[tid] = v > 0.f ? v : expm1f(v);
}

// ---------------- final combine + log_softmax over C=7 ----------------
__global__ void final_kernel(const float* __restrict__ agg, const float* __restrict__ Z,
                             const int* __restrict__ deg, float* __restrict__ out, int n_nodes) {
    int n = blockIdx.x * blockDim.x + threadIdx.x;
    if (n >= n_nodes) return;
    float degv = (float)deg[n];
    if (degv < 1.f) degv = 1.f;
    float v[7];
    float m = -1e30f;
#pragma unroll
    for (int c = 0; c < 7; ++c) {
        v[c] = agg[n * 7 + c] / degv + Z[n * 7 + c];
        m = fmaxf(m, v[c]);
    }
    float s = 0.f;
#pragma unroll
    for (int c = 0; c < 7; ++c) s += expf(v[c] - m);
    float l = logf(s) + m;
#pragma unroll
    for (int c = 0; c < 7; ++c) out[n * 7 + c] = v[c] - l;
}

extern "C" void kernel_launch(void* const* d_in, const int* in_sizes, int n_in,
                              void* d_out, int out_size, void* d_ws, size_t ws_size,
                              hipStream_t stream) {
    const float* x    = (const float*)d_in[0];
    const int*   ei   = (const int*)d_in[1];
    const float* attr = (const float*)d_in[2];
    const float* W0 = (const float*)d_in[3];
    const float* R0 = (const float*)d_in[4];
    const float* B0 = (const float*)d_in[5];
    const float* W1 = (const float*)d_in[6];
    const float* R1 = (const float*)d_in[7];
    const float* B1 = (const float*)d_in[8];
    const float* W2 = (const float*)d_in[9];
    const float* R2 = (const float*)d_in[10];
    const float* B2 = (const float*)d_in[11];
    const float* G0  = (const float*)d_in[12];
    const float* BE0 = (const float*)d_in[13];
    const float* RM0 = (const float*)d_in[14];
    const float* RV0 = (const float*)d_in[15];
    const float* G1  = (const float*)d_in[16];
    const float* BE1 = (const float*)d_in[17];
    const float* RM1 = (const float*)d_in[18];
    const float* RV1 = (const float*)d_in[19];

    const int* src = ei;
    const int* dst = ei + NE;
    float* out = (float*)d_out;

    // workspace layout
    char* ws = (char*)d_ws;
    const size_t BIG = 13u * 1024u * 1024u;  // 13 MB stride per N*64 buffer (needs 12.8 MB)
    int*   deg = (int*)ws;                      // N ints (200 KB)
    float* Ya  = (float*)(ws + 1u * 1024u * 1024u);
    float* Yb  = (float*)(ws + 1u * 1024u * 1024u + 1u * BIG);
    float* agg = (float*)(ws + 1u * 1024u * 1024u + 2u * BIG);
    float* Z   = (float*)(ws + 1u * 1024u * 1024u + 3u * BIG);
    float* h   = (float*)(ws + 1u * 1024u * 1024u + 4u * BIG);

    const int B256 = 256;
    const int gE      = (NE + B256 - 1) / B256;
    const int gN64   = (NN * 64 + B256 - 1) / B256;
    const int gN7    = (NN * 7 + B256 - 1) / B256;
    const int gE16   = (NE * 16 + B256 - 1) / B256;
    const int gN     = (NN + B256 - 1) / B256;

    // degrees (shared by all 3 layers)
    hipMemsetAsync(deg, 0, NN * sizeof(int), stream);
    deg_kernel<<<gE, B256, 0, stream>>>(dst, deg, NE);

    // ---- layer 0: F_IN=32 -> H=64 ----
    matmul3_kernel<32, 64><<<gN64, B256, 0, stream>>>(x, W0, R0, B0, Ya, Yb, Z, NN);
    hipMemsetAsync(agg, 0, (size_t)NN * 64 * sizeof(float), stream);
    scatter64_kernel<<<gE16, B256, 0, stream>>>(src, dst, attr, Ya, Yb, agg, NE);
    bn_elu_kernel<<<gN64, B256, 0, stream>>>(agg, Z, deg, G0, BE0, RM0, RV0, h, NN);

    // ---- layer 1: H=64 -> H=64 ----
    matmul3_kernel<64, 64><<<gN64, B256, 0, stream>>>(h, W1, R1, B1, Ya, Yb, Z, NN);
    hipMemsetAsync(agg, 0, (size_t)NN * 64 * sizeof(float), stream);
    scatter64_kernel<<<gE16, B256, 0, stream>>>(src, dst, attr, Ya, Yb, agg, NE);
    bn_elu_kernel<<<gN64, B256, 0, stream>>>(agg, Z, deg, G1, BE1, RM1, RV1, h, NN);

    // ---- layer 2: H=64 -> C=7, then log_softmax ----
    matmul3_kernel<64, 7><<<gN7, B256, 0, stream>>>(h, W2, R2, B2, Ya, Yb, Z, NN);
    hipMemsetAsync(agg, 0, (size_t)NN * 7 * sizeof(float), stream);
    scatter7_kernel<<<gE, B256, 0, stream>>>(src, dst, attr, Ya, Yb, agg, NE);
    final_kernel<<<gN, B256, 0, stream>>>(agg, Z, deg, out, NN);
}

// Round 2
// 677.432 us; speedup vs baseline: 2.9500x; 2.9500x over previous
//
#include <hip/hip_runtime.h>
#include <math.h>

#define NN 50000
#define NE 800000
#define EPSV 1e-5f

// ---------------- degree count ----------------
__global__ void deg_kernel(const int* __restrict__ dst, int* __restrict__ deg, int E) {
    int e = blockIdx.x * blockDim.x + threadIdx.x;
    if (e < E) atomicAdd(&deg[dst[e]], 1);
}

// ---------------- single-block exclusive scan over deg -> rowptr, cursor ----------------
__global__ void scan_kernel(const int* __restrict__ deg, int* __restrict__ rowptr,
                            int* __restrict__ cursor) {
    __shared__ int part[256];
    int t = threadIdx.x;
    const int CH = (NN + 255) / 256;  // 196
    int start = t * CH;
    int end = start + CH; if (end > NN) end = NN;
    int sum = 0;
    for (int i = start; i < end; ++i) sum += deg[i];
    part[t] = sum;
    __syncthreads();
    if (t == 0) {
        int run = 0;
        for (int i = 0; i < 256; ++i) { int v = part[i]; part[i] = run; run += v; }
    }
    __syncthreads();
    int run = part[t];
    for (int i = start; i < end; ++i) {
        rowptr[i] = run; cursor[i] = run; run += deg[i];
    }
    if (start < NN && end == NN) rowptr[NN] = run;  // last active thread: total == E
}

// ---------------- bucket edges by dst ----------------
__global__ void fill_kernel(const int* __restrict__ src, const int* __restrict__ dst,
                            const float* __restrict__ attr, int* __restrict__ cursor,
                            int* __restrict__ src_s, float* __restrict__ u_s, int E) {
    int e = blockIdx.x * blockDim.x + threadIdx.x;
    if (e >= E) return;
    int pos = atomicAdd(&cursor[dst[e]], 1);
    src_s[pos] = src[e];
    u_s[pos]   = attr[e];
}

// ---------------- dense per-node matmuls: Ya = x@W[0], Yb = x@W[1], Z = x@R + B ----------------
template<int CIN, int COUT>
__global__ void matmul3_kernel(const float* __restrict__ x,
                               const float* __restrict__ W,   // (2, CIN, COUT)
                               const float* __restrict__ R,   // (CIN, COUT)
                               const float* __restrict__ Bb,  // (COUT)
                               float* __restrict__ Ya,
                               float* __restrict__ Yb,
                               float* __restrict__ Z,
                               int n_nodes) {
    int tid = blockIdx.x * blockDim.x + threadIdx.x;
    if (tid >= n_nodes * COUT) return;
    int n = tid / COUT;
    int o = tid - n * COUT;
    const float* xr = x + n * CIN;
    float a = 0.f, b = 0.f, z = 0.f;
#pragma unroll
    for (int c = 0; c < CIN; ++c) {
        float xv = xr[c];
        a = fmaf(xv, W[c * COUT + o], a);
        b = fmaf(xv, W[CIN * COUT + c * COUT + o], b);
        z = fmaf(xv, R[c * COUT + o], z);
    }
    Ya[tid] = a;
    Yb[tid] = b;
    Z[tid]  = z + Bb[o];
}

// ---------------- gather (H=64) + BN + ELU fused: one wave per node, lane = channel ----------------
__global__ void gather64_kernel(const int* __restrict__ rowptr,
                                const int* __restrict__ src_s, const float* __restrict__ u_s,
                                const float* __restrict__ Ya, const float* __restrict__ Yb,
                                const float* __restrict__ Z,
                                const float* __restrict__ G, const float* __restrict__ BE,
                                const float* __restrict__ RM, const float* __restrict__ RV,
                                float* __restrict__ h, int n_nodes) {
    int n = (blockIdx.x * blockDim.x + threadIdx.x) >> 6;
    int lane = threadIdx.x & 63;
    if (n >= n_nodes) return;
    int beg = rowptr[n], end = rowptr[n + 1];
    float acc = 0.f;
    for (int i = beg; i < end; ++i) {
        int s = src_s[i];
        float u = u_s[i];
        acc += (1.f - u) * Ya[s * 64 + lane] + u * Yb[s * 64 + lane];
    }
    float degv = (float)(end - beg);
    if (degv < 1.f) degv = 1.f;
    float v = acc / degv + Z[n * 64 + lane];
    v = (v - RM[lane]) * rsqrtf(RV[lane] + EPSV) * G[lane] + BE[lane];
    h[n * 64 + lane] = v > 0.f ? v : expm1f(v);
}

// ---------------- gather (C=7) + log_softmax fused: 8 lanes per node ----------------
__global__ void gather7_final_kernel(const int* __restrict__ rowptr,
                                     const int* __restrict__ src_s, const float* __restrict__ u_s,
                                     const float* __restrict__ Ya, const float* __restrict__ Yb,
                                     const float* __restrict__ Z,
                                     float* __restrict__ out, int n_nodes) {
    int t = blockIdx.x * blockDim.x + threadIdx.x;
    int n = t >> 3;
    int c = t & 7;
    if (n >= n_nodes) return;
    int beg = rowptr[n], end = rowptr[n + 1];
    float acc = 0.f;
    if (c < 7) {
        for (int i = beg; i < end; ++i) {
            int s = src_s[i];
            float u = u_s[i];
            acc += (1.f - u) * Ya[s * 7 + c] + u * Yb[s * 7 + c];
        }
    }
    float degv = (float)(end - beg);
    if (degv < 1.f) degv = 1.f;
    float v = (c < 7) ? (acc / degv + Z[n * 7 + c]) : -1e30f;
    float m = v;
#pragma unroll
    for (int o = 1; o < 8; o <<= 1) m = fmaxf(m, __shfl_xor(m, o, 8));
    float ex = (c < 7) ? expf(v - m) : 0.f;
    float ssum = ex;
#pragma unroll
    for (int o = 1; o < 8; o <<= 1) ssum += __shfl_xor(ssum, o, 8);
    if (c < 7) out[n * 7 + c] = v - m - logf(ssum);
}

extern "C" void kernel_launch(void* const* d_in, const int* in_sizes, int n_in,
                              void* d_out, int out_size, void* d_ws, size_t ws_size,
                              hipStream_t stream) {
    const float* x    = (const float*)d_in[0];
    const int*   ei   = (const int*)d_in[1];
    const float* attr = (const float*)d_in[2];
    const float* W0 = (const float*)d_in[3];
    const float* R0 = (const float*)d_in[4];
    const float* B0 = (const float*)d_in[5];
    const float* W1 = (const float*)d_in[6];
    const float* R1 = (const float*)d_in[7];
    const float* B1 = (const float*)d_in[8];
    const float* W2 = (const float*)d_in[9];
    const float* R2 = (const float*)d_in[10];
    const float* B2 = (const float*)d_in[11];
    const float* G0  = (const float*)d_in[12];
    const float* BE0 = (const float*)d_in[13];
    const float* RM0 = (const float*)d_in[14];
    const float* RV0 = (const float*)d_in[15];
    const float* G1  = (const float*)d_in[16];
    const float* BE1 = (const float*)d_in[17];
    const float* RM1 = (const float*)d_in[18];
    const float* RV1 = (const float*)d_in[19];

    const int* src = ei;
    const int* dst = ei + NE;
    float* out = (float*)d_out;

    // workspace layout
    char* ws = (char*)d_ws;
    size_t off = 0;
    auto alloc = [&](size_t bytes) { char* p = ws + off; off += (bytes + 255) & ~size_t(255); return p; };
    int*   deg    = (int*)  alloc(NN * sizeof(int));
    int*   rowptr = (int*)  alloc((NN + 1) * sizeof(int));
    int*   cursor = (int*)  alloc(NN * sizeof(int));
    int*   src_s  = (int*)  alloc(NE * sizeof(int));
    float* u_s    = (float*)alloc(NE * sizeof(float));
    float* Ya     = (float*)alloc((size_t)NN * 64 * sizeof(float));
    float* Yb     = (float*)alloc((size_t)NN * 64 * sizeof(float));
    float* Z      = (float*)alloc((size_t)NN * 64 * sizeof(float));
    float* h      = (float*)alloc((size_t)NN * 64 * sizeof(float));

    const int B = 256;
    const int gE    = (NE + B - 1) / B;
    const int gN64  = (NN * 64 + B - 1) / B;
    const int gN7   = (NN * 7 + B - 1) / B;
    const int gN8   = (NN * 8 + B - 1) / B;

    // ---- CSR build (once, reused by all 3 layers) ----
    hipMemsetAsync(deg, 0, NN * sizeof(int), stream);
    deg_kernel<<<gE, B, 0, stream>>>(dst, deg, NE);
    scan_kernel<<<1, 256, 0, stream>>>(deg, rowptr, cursor);
    fill_kernel<<<gE, B, 0, stream>>>(src, dst, attr, cursor, src_s, u_s, NE);

    // ---- layer 0: F_IN=32 -> H=64 ----
    matmul3_kernel<32, 64><<<gN64, B, 0, stream>>>(x, W0, R0, B0, Ya, Yb, Z, NN);
    gather64_kernel<<<gN64, B, 0, stream>>>(rowptr, src_s, u_s, Ya, Yb, Z,
                                            G0, BE0, RM0, RV0, h, NN);

    // ---- layer 1: H=64 -> H=64 ----
    matmul3_kernel<64, 64><<<gN64, B, 0, stream>>>(h, W1, R1, B1, Ya, Yb, Z, NN);
    gather64_kernel<<<gN64, B, 0, stream>>>(rowptr, src_s, u_s, Ya, Yb, Z,
                                            G1, BE1, RM1, RV1, h, NN);

    // ---- layer 2: H=64 -> C=7, then log_softmax ----
    matmul3_kernel<64, 7><<<gN7, B, 0, stream>>>(h, W2, R2, B2, Ya, Yb, Z, NN);
    gather7_final_kernel<<<gN8, B, 0, stream>>>(rowptr, src_s, u_s, Ya, Yb, Z, out, NN);
}

// Round 3
// 608.331 us; speedup vs baseline: 3.2851x; 1.1136x over previous
//
#include <hip/hip_runtime.h>
#include <math.h>

#define NN 50000
#define NE 800000
#define EPSV 1e-5f

// ---------------- degree count ----------------
__global__ void deg_kernel(const int* __restrict__ dst, int* __restrict__ deg, int E) {
    int e = blockIdx.x * blockDim.x + threadIdx.x;
    if (e < E) atomicAdd(&deg[dst[e]], 1);
}

// ---------------- single-block 1024-thread exclusive scan over deg -> rowptr, cursor ----------------
__global__ __launch_bounds__(1024) void scan_kernel(const int* __restrict__ deg,
                                                    int* __restrict__ rowptr,
                                                    int* __restrict__ cursor) {
    __shared__ int wsum[16];
    int t = threadIdx.x;                      // 0..1023
    const int CH = (NN + 1023) / 1024;        // 49
    int start = t * CH;
    int end = start + CH; if (end > NN) end = NN;
    int sum = 0;
    for (int i = start; i < end; ++i) sum += deg[i];

    int lane = t & 63, w = t >> 6;
    // inclusive scan within wave (64 lanes)
    int v = sum;
#pragma unroll
    for (int o = 1; o < 64; o <<= 1) {
        int nv = __shfl_up(v, o, 64);
        if (lane >= o) v += nv;
    }
    if (lane == 63) wsum[w] = v;
    __syncthreads();
    if (w == 0 && lane < 16) {
        int s_ = wsum[lane];
#pragma unroll
        for (int o = 1; o < 16; o <<= 1) {
            int nv = __shfl_up(s_, o, 64);
            if (lane >= o) s_ += nv;
        }
        wsum[lane] = s_;
    }
    __syncthreads();
    int excl = v - sum + (w > 0 ? wsum[w - 1] : 0);
    int run = excl;
    for (int i = start; i < end; ++i) {
        rowptr[i] = run; cursor[i] = run; run += deg[i];
    }
    if (t == 1023) rowptr[NN] = run;  // t=1023 has empty range: run == total == E
}

// ---------------- bucket edges by dst: packed 8 B record ----------------
__global__ void fill_kernel(const int* __restrict__ src, const int* __restrict__ dst,
                            const float* __restrict__ attr, int* __restrict__ cursor,
                            int2* __restrict__ es, int E) {
    int e = blockIdx.x * blockDim.x + threadIdx.x;
    if (e >= E) return;
    int pos = atomicAdd(&cursor[dst[e]], 1);
    int2 rec;
    rec.x = src[e];
    rec.y = __float_as_int(attr[e]);
    es[pos] = rec;
}

// ---------------- dense per-node matmuls: Yab interleaved {a,b}, Z = x@R + B ----------------
template<int CIN, int COUT>
__global__ void matmul3_kernel(const float* __restrict__ x,
                               const float* __restrict__ W,   // (2, CIN, COUT)
                               const float* __restrict__ R,   // (CIN, COUT)
                               const float* __restrict__ Bb,  // (COUT)
                               float* __restrict__ Yab,       // (n, COUT, 2) interleaved
                               float* __restrict__ Z,
                               int n_nodes) {
    int tid = blockIdx.x * blockDim.x + threadIdx.x;
    if (tid >= n_nodes * COUT) return;
    int n = tid / COUT;
    int o = tid - n * COUT;
    const float* xr = x + n * CIN;
    float a = 0.f, b = 0.f, z = 0.f;
#pragma unroll
    for (int c = 0; c < CIN; ++c) {
        float xv = xr[c];
        a = fmaf(xv, W[c * COUT + o], a);
        b = fmaf(xv, W[CIN * COUT + c * COUT + o], b);
        z = fmaf(xv, R[c * COUT + o], z);
    }
    float2 ab; ab.x = a; ab.y = b;
    *reinterpret_cast<float2*>(Yab + (size_t)n * 2 * COUT + 2 * o) = ab;
    Z[tid] = z + Bb[o];
}

// ---------------- gather (H=64) + BN + ELU fused: one wave per node, lane = channel ----------------
__global__ void gather64_kernel(const int* __restrict__ rowptr,
                                const int2* __restrict__ es,
                                const float* __restrict__ Yab,
                                const float* __restrict__ Z,
                                const float* __restrict__ G, const float* __restrict__ BE,
                                const float* __restrict__ RM, const float* __restrict__ RV,
                                float* __restrict__ h, int n_nodes) {
    int n = (blockIdx.x * blockDim.x + threadIdx.x) >> 6;
    int lane = threadIdx.x & 63;
    if (n >= n_nodes) return;
    int beg = rowptr[n], end = rowptr[n + 1];
    float acc0 = 0.f, acc1 = 0.f;
    int i = beg;
    for (; i + 1 < end; i += 2) {
        int2 e0 = es[i];
        int2 e1 = es[i + 1];
        float u0 = __int_as_float(e0.y);
        float u1 = __int_as_float(e1.y);
        float2 ab0 = *reinterpret_cast<const float2*>(Yab + (size_t)e0.x * 128 + 2 * lane);
        float2 ab1 = *reinterpret_cast<const float2*>(Yab + (size_t)e1.x * 128 + 2 * lane);
        acc0 += (1.f - u0) * ab0.x + u0 * ab0.y;
        acc1 += (1.f - u1) * ab1.x + u1 * ab1.y;
    }
    if (i < end) {
        int2 e0 = es[i];
        float u0 = __int_as_float(e0.y);
        float2 ab0 = *reinterpret_cast<const float2*>(Yab + (size_t)e0.x * 128 + 2 * lane);
        acc0 += (1.f - u0) * ab0.x + u0 * ab0.y;
    }
    float acc = acc0 + acc1;
    float degv = (float)(end - beg);
    if (degv < 1.f) degv = 1.f;
    float v = acc / degv + Z[n * 64 + lane];
    v = (v - RM[lane]) * rsqrtf(RV[lane] + EPSV) * G[lane] + BE[lane];
    h[n * 64 + lane] = v > 0.f ? v : expm1f(v);
}

// ---------------- gather (C=7) + log_softmax fused: 8 lanes per node ----------------
__global__ void gather7_final_kernel(const int* __restrict__ rowptr,
                                     const int2* __restrict__ es,
                                     const float* __restrict__ Yab,  // (n,7,2)
                                     const float* __restrict__ Z,
                                     float* __restrict__ out, int n_nodes) {
    int t = blockIdx.x * blockDim.x + threadIdx.x;
    int n = t >> 3;
    int c = t & 7;
    if (n >= n_nodes) return;
    int beg = rowptr[n], end = rowptr[n + 1];
    float acc = 0.f;
    if (c < 7) {
        for (int i = beg; i < end; ++i) {
            int2 e0 = es[i];
            float u = __int_as_float(e0.y);
            float2 ab = *reinterpret_cast<const float2*>(Yab + (size_t)e0.x * 14 + 2 * c);
            acc += (1.f - u) * ab.x + u * ab.y;
        }
    }
    float degv = (float)(end - beg);
    if (degv < 1.f) degv = 1.f;
    float v = (c < 7) ? (acc / degv + Z[n * 7 + c]) : -1e30f;
    float m = v;
#pragma unroll
    for (int o = 1; o < 8; o <<= 1) m = fmaxf(m, __shfl_xor(m, o, 8));
    float ex = (c < 7) ? expf(v - m) : 0.f;
    float ssum = ex;
#pragma unroll
    for (int o = 1; o < 8; o <<= 1) ssum += __shfl_xor(ssum, o, 8);
    if (c < 7) out[n * 7 + c] = v - m - logf(ssum);
}

extern "C" void kernel_launch(void* const* d_in, const int* in_sizes, int n_in,
                              void* d_out, int out_size, void* d_ws, size_t ws_size,
                              hipStream_t stream) {
    const float* x    = (const float*)d_in[0];
    const int*   ei   = (const int*)d_in[1];
    const float* attr = (const float*)d_in[2];
    const float* W0 = (const float*)d_in[3];
    const float* R0 = (const float*)d_in[4];
    const float* B0 = (const float*)d_in[5];
    const float* W1 = (const float*)d_in[6];
    const float* R1 = (const float*)d_in[7];
    const float* B1 = (const float*)d_in[8];
    const float* W2 = (const float*)d_in[9];
    const float* R2 = (const float*)d_in[10];
    const float* B2 = (const float*)d_in[11];
    const float* G0  = (const float*)d_in[12];
    const float* BE0 = (const float*)d_in[13];
    const float* RM0 = (const float*)d_in[14];
    const float* RV0 = (const float*)d_in[15];
    const float* G1  = (const float*)d_in[16];
    const float* BE1 = (const float*)d_in[17];
    const float* RM1 = (const float*)d_in[18];
    const float* RV1 = (const float*)d_in[19];

    const int* src = ei;
    const int* dst = ei + NE;
    float* out = (float*)d_out;

    // workspace layout
    char* ws = (char*)d_ws;
    size_t off = 0;
    auto alloc = [&](size_t bytes) { char* p = ws + off; off += (bytes + 255) & ~size_t(255); return p; };
    int*   deg    = (int*)  alloc(NN * sizeof(int));
    int*   rowptr = (int*)  alloc((NN + 1) * sizeof(int));
    int*   cursor = (int*)  alloc(NN * sizeof(int));
    int2*  es     = (int2*) alloc((size_t)NE * sizeof(int2));
    float* Yab    = (float*)alloc((size_t)NN * 128 * sizeof(float));
    float* Z      = (float*)alloc((size_t)NN * 64 * sizeof(float));
    float* h      = (float*)alloc((size_t)NN * 64 * sizeof(float));

    const int B = 256;
    const int gE    = (NE + B - 1) / B;
    const int gN64  = (NN * 64 + B - 1) / B;
    const int gN7   = (NN * 7 + B - 1) / B;
    const int gN8   = (NN * 8 + B - 1) / B;

    // ---- CSR build (once, reused by all 3 layers) ----
    hipMemsetAsync(deg, 0, NN * sizeof(int), stream);
    deg_kernel<<<gE, B, 0, stream>>>(dst, deg, NE);
    scan_kernel<<<1, 1024, 0, stream>>>(deg, rowptr, cursor);
    fill_kernel<<<gE, B, 0, stream>>>(src, dst, attr, cursor, es, NE);

    // ---- layer 0: F_IN=32 -> H=64 ----
    matmul3_kernel<32, 64><<<gN64, B, 0, stream>>>(x, W0, R0, B0, Yab, Z, NN);
    gather64_kernel<<<gN64, B, 0, stream>>>(rowptr, es, Yab, Z, G0, BE0, RM0, RV0, h, NN);

    // ---- layer 1: H=64 -> H=64 ----
    matmul3_kernel<64, 64><<<gN64, B, 0, stream>>>(h, W1, R1, B1, Yab, Z, NN);
    gather64_kernel<<<gN64, B, 0, stream>>>(rowptr, es, Yab, Z, G1, BE1, RM1, RV1, h, NN);

    // ---- layer 2: H=64 -> C=7, then log_softmax ----
    matmul3_kernel<64, 7><<<gN7, B, 0, stream>>>(h, W2, R2, B2, Yab, Z, NN);
    gather7_final_kernel<<<gN8, B, 0, stream>>>(rowptr, es, Yab, Z, out, NN);
}

// Round 4
// 512.551 us; speedup vs baseline: 3.8990x; 1.1869x over previous
//
#include <hip/hip_runtime.h>
#include <math.h>

#define NN 50000
#define NE 800000
#define EPSV 1e-5f
#define SCAN_NB 49   // ceil(NN / 1024)

// ---------------- degree count ----------------
__global__ void deg_kernel(const int* __restrict__ dst, int* __restrict__ deg, int E) {
    int e = blockIdx.x * blockDim.x + threadIdx.x;
    if (e < E) atomicAdd(&deg[dst[e]], 1);
}

// ---------------- 3-phase grid-wide exclusive scan of deg -> rowptr, cursor ----------------
__global__ void scan_phaseA(const int* __restrict__ deg, int* __restrict__ blocksum) {
    __shared__ int wsums[4];
    int t = threadIdx.x;
    int base = blockIdx.x * 1024 + t * 4;
    int s = 0;
    if (base + 3 < NN) {
        int4 d = *reinterpret_cast<const int4*>(deg + base);
        s = d.x + d.y + d.z + d.w;
    } else {
        for (int j = 0; j < 4; ++j) if (base + j < NN) s += deg[base + j];
    }
#pragma unroll
    for (int o = 1; o < 64; o <<= 1) s += __shfl_xor(s, o, 64);
    if ((t & 63) == 0) wsums[t >> 6] = s;
    __syncthreads();
    if (t == 0) blocksum[blockIdx.x] = wsums[0] + wsums[1] + wsums[2] + wsums[3];
}

__global__ void scan_phaseB(int* __restrict__ blocksum) {
    int t = threadIdx.x;  // 64 threads
    int v = (t < SCAN_NB) ? blocksum[t] : 0;
    int incl = v;
#pragma unroll
    for (int o = 1; o < 64; o <<= 1) {
        int nv = __shfl_up(incl, o, 64);
        if (t >= o) incl += nv;
    }
    if (t < SCAN_NB) blocksum[t] = incl - v;  // exclusive
}

__global__ void scan_phaseC(const int* __restrict__ deg, const int* __restrict__ blocksum,
                            int* __restrict__ rowptr, int* __restrict__ cursor) {
    __shared__ int woff[4];
    int t = threadIdx.x;
    int base = blockIdx.x * 1024 + t * 4;
    int d0 = 0, d1 = 0, d2 = 0, d3 = 0;
    if (base + 3 < NN) {
        int4 d = *reinterpret_cast<const int4*>(deg + base);
        d0 = d.x; d1 = d.y; d2 = d.z; d3 = d.w;
    } else {
        if (base + 0 < NN) d0 = deg[base + 0];
        if (base + 1 < NN) d1 = deg[base + 1];
        if (base + 2 < NN) d2 = deg[base + 2];
        if (base + 3 < NN) d3 = deg[base + 3];
    }
    int ts = d0 + d1 + d2 + d3;
    int lane = t & 63, w = t >> 6;
    int incl = ts;
#pragma unroll
    for (int o = 1; o < 64; o <<= 1) {
        int nv = __shfl_up(incl, o, 64);
        if (lane >= o) incl += nv;
    }
    if (lane == 63) woff[w] = incl;
    __syncthreads();
    if (t == 0) {
        int r = 0;
#pragma unroll
        for (int i = 0; i < 4; ++i) { int v = woff[i]; woff[i] = r; r += v; }
    }
    __syncthreads();
    int run = blocksum[blockIdx.x] + woff[w] + incl - ts;
    int r0 = run, r1 = r0 + d0, r2 = r1 + d1, r3 = r2 + d2;
    if (base + 3 < NN) {
        int4 rv; rv.x = r0; rv.y = r1; rv.z = r2; rv.w = r3;
        *reinterpret_cast<int4*>(rowptr + base) = rv;
        *reinterpret_cast<int4*>(cursor + base) = rv;
    } else {
        if (base + 0 < NN) { rowptr[base + 0] = r0; cursor[base + 0] = r0; }
        if (base + 1 < NN) { rowptr[base + 1] = r1; cursor[base + 1] = r1; }
        if (base + 2 < NN) { rowptr[base + 2] = r2; cursor[base + 2] = r2; }
    }
    if (blockIdx.x == 0 && t == 0) rowptr[NN] = NE;  // total degree is always E
}

// ---------------- bucket edges by dst: packed 8 B record ----------------
__global__ void fill_kernel(const int* __restrict__ src, const int* __restrict__ dst,
                            const float* __restrict__ attr, int* __restrict__ cursor,
                            int2* __restrict__ es, int E) {
    int e = blockIdx.x * blockDim.x + threadIdx.x;
    if (e >= E) return;
    int pos = atomicAdd(&cursor[dst[e]], 1);
    int2 rec;
    rec.x = src[e];
    rec.y = __float_as_int(attr[e]);
    es[pos] = rec;
}

// ---------------- dense per-node matmuls: Yab interleaved {a,b}, Z = x@R + B ----------------
template<int CIN, int COUT>
__global__ void matmul3_kernel(const float* __restrict__ x,
                               const float* __restrict__ W,   // (2, CIN, COUT)
                               const float* __restrict__ R,   // (CIN, COUT)
                               const float* __restrict__ Bb,  // (COUT)
                               float* __restrict__ Yab,       // (n, COUT, 2) interleaved
                               float* __restrict__ Z,
                               int n_nodes) {
    int tid = blockIdx.x * blockDim.x + threadIdx.x;
    if (tid >= n_nodes * COUT) return;
    int n = tid / COUT;
    int o = tid - n * COUT;
    const float* xr = x + n * CIN;
    float a = 0.f, b = 0.f, z = 0.f;
#pragma unroll
    for (int c = 0; c < CIN; ++c) {
        float xv = xr[c];
        a = fmaf(xv, W[c * COUT + o], a);
        b = fmaf(xv, W[CIN * COUT + c * COUT + o], b);
        z = fmaf(xv, R[c * COUT + o], z);
    }
    float2 ab; ab.x = a; ab.y = b;
    *reinterpret_cast<float2*>(Yab + (size_t)n * 2 * COUT + 2 * o) = ab;
    Z[tid] = z + Bb[o];
}

// ---------------- gather (H=64) + BN + ELU fused: one wave per node, lane = channel ----------------
__global__ void gather64_kernel(const int* __restrict__ rowptr,
                                const int2* __restrict__ es,
                                const float* __restrict__ Yab,
                                const float* __restrict__ Z,
                                const float* __restrict__ G, const float* __restrict__ BE,
                                const float* __restrict__ RM, const float* __restrict__ RV,
                                float* __restrict__ h, int n_nodes) {
    int n = (blockIdx.x * blockDim.x + threadIdx.x) >> 6;
    int lane = threadIdx.x & 63;
    if (n >= n_nodes) return;
    int beg = rowptr[n], end = rowptr[n + 1];
    float acc0 = 0.f, acc1 = 0.f;
    int i = beg;
    for (; i + 1 < end; i += 2) {
        int2 e0 = es[i];
        int2 e1 = es[i + 1];
        float u0 = __int_as_float(e0.y);
        float u1 = __int_as_float(e1.y);
        float2 ab0 = *reinterpret_cast<const float2*>(Yab + (size_t)e0.x * 128 + 2 * lane);
        float2 ab1 = *reinterpret_cast<const float2*>(Yab + (size_t)e1.x * 128 + 2 * lane);
        acc0 += (1.f - u0) * ab0.x + u0 * ab0.y;
        acc1 += (1.f - u1) * ab1.x + u1 * ab1.y;
    }
    if (i < end) {
        int2 e0 = es[i];
        float u0 = __int_as_float(e0.y);
        float2 ab0 = *reinterpret_cast<const float2*>(Yab + (size_t)e0.x * 128 + 2 * lane);
        acc0 += (1.f - u0) * ab0.x + u0 * ab0.y;
    }
    float acc = acc0 + acc1;
    float degv = (float)(end - beg);
    if (degv < 1.f) degv = 1.f;
    float v = acc / degv + Z[n * 64 + lane];
    v = (v - RM[lane]) * rsqrtf(RV[lane] + EPSV) * G[lane] + BE[lane];
    h[n * 64 + lane] = v > 0.f ? v : expm1f(v);
}

// ---------------- gather (C=7) + log_softmax fused: 8 lanes per node ----------------
__global__ void gather7_final_kernel(const int* __restrict__ rowptr,
                                     const int2* __restrict__ es,
                                     const float* __restrict__ Yab,  // (n,7,2)
                                     const float* __restrict__ Z,
                                     float* __restrict__ out, int n_nodes) {
    int t = blockIdx.x * blockDim.x + threadIdx.x;
    int n = t >> 3;
    int c = t & 7;
    if (n >= n_nodes) return;
    int beg = rowptr[n], end = rowptr[n + 1];
    float acc = 0.f;
    if (c < 7) {
        for (int i = beg; i < end; ++i) {
            int2 e0 = es[i];
            float u = __int_as_float(e0.y);
            float2 ab = *reinterpret_cast<const float2*>(Yab + (size_t)e0.x * 14 + 2 * c);
            acc += (1.f - u) * ab.x + u * ab.y;
        }
    }
    float degv = (float)(end - beg);
    if (degv < 1.f) degv = 1.f;
    float v = (c < 7) ? (acc / degv + Z[n * 7 + c]) : -1e30f;
    float m = v;
#pragma unroll
    for (int o = 1; o < 8; o <<= 1) m = fmaxf(m, __shfl_xor(m, o, 8));
    float ex = (c < 7) ? expf(v - m) : 0.f;
    float ssum = ex;
#pragma unroll
    for (int o = 1; o < 8; o <<= 1) ssum += __shfl_xor(ssum, o, 8);
    if (c < 7) out[n * 7 + c] = v - m - logf(ssum);
}

extern "C" void kernel_launch(void* const* d_in, const int* in_sizes, int n_in,
                              void* d_out, int out_size, void* d_ws, size_t ws_size,
                              hipStream_t stream) {
    const float* x    = (const float*)d_in[0];
    const int*   ei   = (const int*)d_in[1];
    const float* attr = (const float*)d_in[2];
    const float* W0 = (const float*)d_in[3];
    const float* R0 = (const float*)d_in[4];
    const float* B0 = (const float*)d_in[5];
    const float* W1 = (const float*)d_in[6];
    const float* R1 = (const float*)d_in[7];
    const float* B1 = (const float*)d_in[8];
    const float* W2 = (const float*)d_in[9];
    const float* R2 = (const float*)d_in[10];
    const float* B2 = (const float*)d_in[11];
    const float* G0  = (const float*)d_in[12];
    const float* BE0 = (const float*)d_in[13];
    const float* RM0 = (const float*)d_in[14];
    const float* RV0 = (const float*)d_in[15];
    const float* G1  = (const float*)d_in[16];
    const float* BE1 = (const float*)d_in[17];
    const float* RM1 = (const float*)d_in[18];
    const float* RV1 = (const float*)d_in[19];

    const int* src = ei;
    const int* dst = ei + NE;
    float* out = (float*)d_out;

    // workspace layout
    char* ws = (char*)d_ws;
    size_t off = 0;
    auto alloc = [&](size_t bytes) { char* p = ws + off; off += (bytes + 255) & ~size_t(255); return p; };
    int*   deg      = (int*)  alloc(NN * sizeof(int));
    int*   rowptr   = (int*)  alloc((NN + 1) * sizeof(int));
    int*   cursor   = (int*)  alloc(NN * sizeof(int));
    int*   blocksum = (int*)  alloc(SCAN_NB * sizeof(int));
    int2*  es       = (int2*) alloc((size_t)NE * sizeof(int2));
    float* Yab      = (float*)alloc((size_t)NN * 128 * sizeof(float));
    float* Z        = (float*)alloc((size_t)NN * 64 * sizeof(float));
    float* h        = (float*)alloc((size_t)NN * 64 * sizeof(float));

    const int B = 256;
    const int gE    = (NE + B - 1) / B;
    const int gN64  = (NN * 64 + B - 1) / B;
    const int gN7   = (NN * 7 + B - 1) / B;
    const int gN8   = (NN * 8 + B - 1) / B;

    // ---- CSR build (once, reused by all 3 layers) ----
    hipMemsetAsync(deg, 0, NN * sizeof(int), stream);
    deg_kernel<<<gE, B, 0, stream>>>(dst, deg, NE);
    scan_phaseA<<<SCAN_NB, 256, 0, stream>>>(deg, blocksum);
    scan_phaseB<<<1, 64, 0, stream>>>(blocksum);
    scan_phaseC<<<SCAN_NB, 256, 0, stream>>>(deg, blocksum, rowptr, cursor);
    fill_kernel<<<gE, B, 0, stream>>>(src, dst, attr, cursor, es, NE);

    // ---- layer 0: F_IN=32 -> H=64 ----
    matmul3_kernel<32, 64><<<gN64, B, 0, stream>>>(x, W0, R0, B0, Yab, Z, NN);
    gather64_kernel<<<gN64, B, 0, stream>>>(rowptr, es, Yab, Z, G0, BE0, RM0, RV0, h, NN);

    // ---- layer 1: H=64 -> H=64 ----
    matmul3_kernel<64, 64><<<gN64, B, 0, stream>>>(h, W1, R1, B1, Yab, Z, NN);
    gather64_kernel<<<gN64, B, 0, stream>>>(rowptr, es, Yab, Z, G1, BE1, RM1, RV1, h, NN);

    // ---- layer 2: H=64 -> C=7, then log_softmax ----
    matmul3_kernel<64, 7><<<gN7, B, 0, stream>>>(h, W2, R2, B2, Yab, Z, NN);
    gather7_final_kernel<<<gN8, B, 0, stream>>>(rowptr, es, Yab, Z, out, NN);
}